// Round 4
// baseline (812.987 us; speedup 1.0000x reference)
//
#include <hip/hip_runtime.h>
#include <math.h>

#define VSZ 50257
#define HSZ 1024
#define LSZ 2048
#define SHIFT 60.0f

typedef __attribute__((ext_vector_type(8))) short bf16x8;
typedef __attribute__((ext_vector_type(4))) float f32x4;

__device__ __forceinline__ unsigned short f2bf(float f) {
  unsigned int u = __float_as_uint(f);
  u += 0x7FFFu + ((u >> 16) & 1u);  // RNE
  return (unsigned short)(u >> 16);
}

__device__ __forceinline__ float gru1(float gr, float hr, float gz, float hz,
                                      float gn, float ghn, float h0v) {
  float r = 1.f / (1.f + expf(-(gr + hr)));
  float z = 1.f / (1.f + expf(-(gz + hz)));
  float n = tanhf(gn + r * ghn);
  return (1.f - z) * n + z * h0v;
}

// ============ K1: attention GEMV + zero-init + fp32->bf16 conversion ============
// blocks 0..511: attnw GEMV (4 rows/block). 512..708: zero out[0..V).
// 709: zero score_c. 710: zero acc+psum+cnts+final_weights. 711..1478: convert enc|Wc to bf16.
__global__ void k_attn(const float* __restrict__ Waw, const float* __restrict__ baw,
                       const int* __restrict__ din, const float* __restrict__ emb,
                       const float* __restrict__ h0, const float* __restrict__ enc,
                       const float* __restrict__ Wc, float* __restrict__ attnw,
                       float* __restrict__ out, float* __restrict__ score_c,
                       float* __restrict__ acc, float* __restrict__ psum,
                       int* __restrict__ cnts, unsigned short* __restrict__ bfbuf) {
  int bid = blockIdx.x, tid = threadIdx.x;
  if (bid < 512) {
    int gw = bid * 4 + (tid >> 6);
    int lane = tid & 63;
    const float4* row = (const float4*)(Waw + (size_t)gw * 2048);
    const float4* e4 = (const float4*)(emb + (size_t)din[0] * HSZ);
    const float4* h4 = (const float4*)h0;
    float s = 0.f;
#pragma unroll
    for (int j = 0; j < 4; ++j) {
      float4 a = row[lane + 64 * j];
      float4 b = e4[lane + 64 * j];
      s += a.x * b.x + a.y * b.y + a.z * b.z + a.w * b.w;
    }
#pragma unroll
    for (int j = 0; j < 4; ++j) {
      float4 a = row[256 + lane + 64 * j];
      float4 b = h4[lane + 64 * j];
      s += a.x * b.x + a.y * b.y + a.z * b.z + a.w * b.w;
    }
#pragma unroll
    for (int o = 32; o > 0; o >>= 1) s += __shfl_down(s, o, 64);
    if (lane == 0) attnw[gw] = s + baw[gw];
  } else if (bid < 709) {
    int v = (bid - 512) * 256 + tid;
    if (v < VSZ) out[v] = 0.f;
  } else if (bid == 709) {
#pragma unroll
    for (int k = 0; k < 8; ++k) score_c[tid + 256 * k] = 0.f;
  } else if (bid == 710) {
#pragma unroll
    for (int k = 0; k < 4; ++k) acc[tid + 256 * k] = 0.f;
#pragma unroll
    for (int k = 0; k < 4; ++k) out[VSZ + HSZ + tid + 256 * k] = 0.f;  // final_weights zero
    if (tid == 0) { psum[0] = 0.f; cnts[0] = 0; cnts[1] = 0; }
  } else {
    // conversion: 768 blocks x 256 threads x 4 float4 = 786432 float4s
    // first 524288 float4 from enc, then 262144 from Wc
    int cb = bid - 711;
#pragma unroll
    for (int c = 0; c < 4; ++c) {
      int g = cb * 1024 + c * 256 + tid;
      float4 v;
      if (g < 524288) v = ((const float4*)enc)[g];
      else            v = ((const float4*)Wc)[g - 524288];
      ushort4 o;
      o.x = f2bf(v.x); o.y = f2bf(v.y); o.z = f2bf(v.z); o.w = f2bf(v.w);
      *(ushort4*)(bfbuf + (size_t)g * 4) = o;
    }
  }
}

// ============ K2: in-block softmax(attnw) + attn_applied accumulate ============
__global__ void k_attn_apply(const float* __restrict__ attnw, const float* __restrict__ enc,
                             float* __restrict__ acc) {
  __shared__ float red[256];
  __shared__ float sw[64];
  int bid = blockIdx.x, t = threadIdx.x;
  int hb = bid & 3, mb = bid >> 2;
  float m = -1e30f;
  for (int i = t; i < LSZ; i += 256) m = fmaxf(m, attnw[i]);
  red[t] = m; __syncthreads();
  for (int s = 128; s > 0; s >>= 1) { if (t < s) red[t] = fmaxf(red[t], red[t + s]); __syncthreads(); }
  float gmax = red[0]; __syncthreads();
  float sum = 0.f;
  for (int i = t; i < LSZ; i += 256) sum += expf(attnw[i] - gmax);
  red[t] = sum; __syncthreads();
  for (int s = 128; s > 0; s >>= 1) { if (t < s) red[t] += red[t + s]; __syncthreads(); }
  float inv = 1.f / red[0];
  if (t < 64) sw[t] = expf(attnw[mb * 64 + t] - gmax) * inv;
  __syncthreads();
  int h = hb * 256 + t;
  float s = 0.f;
#pragma unroll 4
  for (int j = 0; j < 64; ++j) s = fmaf(sw[j], enc[(size_t)(mb * 64 + j) * HSZ + h], s);
  atomicAdd(&acc[h], s);
}

// ============ K3: rnn_in = relu(W_attn_u @ [emb0|attn_applied] + b) ============
__global__ void k_rnn(const float* __restrict__ Wau, const float* __restrict__ bau,
                      const int* __restrict__ din, const float* __restrict__ emb,
                      const float* __restrict__ acc, float* __restrict__ rnn_in) {
  int gw = blockIdx.x * 4 + (threadIdx.x >> 6);
  int lane = threadIdx.x & 63;
  const float4* row = (const float4*)(Wau + (size_t)gw * 2048);
  const float4* e4 = (const float4*)(emb + (size_t)din[0] * HSZ);
  const float4* a4 = (const float4*)acc;
  float s = 0.f;
#pragma unroll
  for (int j = 0; j < 4; ++j) {
    float4 a = row[lane + 64 * j];
    float4 b = e4[lane + 64 * j];
    s += a.x * b.x + a.y * b.y + a.z * b.z + a.w * b.w;
  }
#pragma unroll
  for (int j = 0; j < 4; ++j) {
    float4 a = row[256 + lane + 64 * j];
    float4 b = a4[lane + 64 * j];
    s += a.x * b.x + a.y * b.y + a.z * b.z + a.w * b.w;
  }
#pragma unroll
  for (int o = 32; o > 0; o >>= 1) s += __shfl_down(s, o, 64);
  if (lane == 0) rnn_in[gw] = fmaxf(s + bau[gw], 0.f);
}

// ============ K4: gi/gh gates (6144 rows) + wait-free last-block GRU tail ============
__global__ void k_gates(const float* __restrict__ Wih, const float* __restrict__ bih,
                        const float* __restrict__ xin, const float* __restrict__ Whh,
                        const float* __restrict__ bhh, const float* __restrict__ h0,
                        float* __restrict__ y, float* __restrict__ h_new,
                        float* __restrict__ out, int* __restrict__ cnt) {
  int bid = blockIdx.x, tid = threadIdx.x;
  int gw = bid * 4 + (tid >> 6);
  int lane = tid & 63;
  const float* W; const float* x; float bv; int r;
  if (gw < 3 * HSZ) { W = Wih; x = xin; r = gw; bv = bih[r]; }
  else              { W = Whh; x = h0;  r = gw - 3 * HSZ; bv = bhh[r]; }
  const float4* row = (const float4*)(W + (size_t)r * HSZ);
  const float4* xv = (const float4*)x;
  float s = 0.f;
#pragma unroll
  for (int j = 0; j < 4; ++j) {
    float4 a = row[lane + 64 * j];
    float4 b = xv[lane + 64 * j];
    s += a.x * b.x + a.y * b.y + a.z * b.z + a.w * b.w;
  }
#pragma unroll
  for (int o = 32; o > 0; o >>= 1) s += __shfl_down(s, o, 64);
  if (lane == 0) y[gw] = s + bv;
  // ---- wait-free last-block GRU tail (no spin: the 1536th finisher does it) ----
  __shared__ int lastf;
  __syncthreads();  // drains this block's y stores (vmcnt) before the signal
  if (tid == 0) { __threadfence(); lastf = (atomicAdd(cnt, 1) == 1535); }
  __syncthreads();
  if (lastf) {
    __threadfence();  // acquire: all blocks' y visible
    const float4* G  = (const float4*)y;
    const float4* Hh = (const float4*)(y + 3072);
    const float4* H0 = (const float4*)h0;
    float4 gr = G[tid], gz = G[256 + tid], gn = G[512 + tid];
    float4 hr = Hh[tid], hz = Hh[256 + tid], hn4 = Hh[512 + tid];
    float4 h0v = H0[tid];
    float4 xo;
    xo.x = gru1(gr.x, hr.x, gz.x, hz.x, gn.x, hn4.x, h0v.x);
    xo.y = gru1(gr.y, hr.y, gz.y, hz.y, gn.y, hn4.y, h0v.y);
    xo.z = gru1(gr.z, hr.z, gz.z, hz.z, gn.z, hn4.z, h0v.z);
    xo.w = gru1(gr.w, hr.w, gz.w, hz.w, gn.w, hn4.w, h0v.w);
    ((float4*)h_new)[tid] = xo;
    int b0 = VSZ + tid * 4;  // out+VSZ only 4B-aligned -> scalar stores
    out[b0] = xo.x; out[b0 + 1] = xo.y; out[b0 + 2] = xo.z; out[b0 + 3] = xo.w;
  }
}

// ============ K5: fused bf16-MFMA copy GEMM + vocab GEMV + fused exp-sum ============
// blocks 0..511: GEMM 64x64 tiles (hidden under the BW-bound GEMV, as in baseline).
// 512..6794: vocab GEMV (8 rows/block); each block folds exp(score_g) of its own rows
// into psum (no cross-block dep). Wait-free last-block tail sums exp(score_c).
__global__ __launch_bounds__(256) void k_huge(
    const unsigned short* __restrict__ encB, const unsigned short* __restrict__ WcB,
    const float* __restrict__ bc, const float* __restrict__ hvec,
    const float* __restrict__ Wg, const float* __restrict__ bg,
    const float* __restrict__ h_new, float* __restrict__ score,
    float* __restrict__ psum, int* __restrict__ cnt) {
  int bid = blockIdx.x, tid = threadIdx.x;
  int wave = tid >> 6, lane = tid & 63;
  __shared__ float pr[4];
  __shared__ int lastf;
  if (bid < 512) {
    int l0 = (bid >> 4) * 64 + wave * 16;  // this wave's 16-row strip
    int h0r = (bid & 15) * 64;
    int col = lane & 15, quad = lane >> 4;
    f32x4 accf[4] = {};
    const unsigned short* arow = encB + ((size_t)(l0 + col) << 10) + quad * 8;
#pragma unroll 4
    for (int k0 = 0; k0 < HSZ; k0 += 32) {
      bf16x8 a = *(const bf16x8*)(arow + k0);
#pragma unroll
      for (int ht = 0; ht < 4; ++ht) {
        bf16x8 b = *(const bf16x8*)(WcB + ((size_t)(h0r + ht * 16 + col) << 10) + k0 + quad * 8);
        accf[ht] = __builtin_amdgcn_mfma_f32_16x16x32_bf16(a, b, accf[ht], 0, 0, 0);
      }
    }
    float rsum[4] = {0.f, 0.f, 0.f, 0.f};
#pragma unroll
    for (int ht = 0; ht < 4; ++ht) {
      int h = h0r + ht * 16 + col;
      float bch = bc[h], hw = hvec[h];
#pragma unroll
      for (int r = 0; r < 4; ++r) rsum[r] += tanhf(accf[ht][r] + bch) * hw;
    }
#pragma unroll
    for (int o = 1; o < 16; o <<= 1) {
#pragma unroll
      for (int r = 0; r < 4; ++r) rsum[r] += __shfl_xor(rsum[r], o, 64);
    }
    if (col == 0) {
      int lrow = l0 + quad * 4;  // C/D: row = quad*4 + reg
#pragma unroll
      for (int r = 0; r < 4; ++r) atomicAdd(&score[VSZ + lrow + r], rsum[r]);
    }
  } else {
    int r0 = (bid - 512) * 8 + wave * 2;
    int ra = r0 < VSZ ? r0 : VSZ - 1;
    int rb = r0 + 1 < VSZ ? r0 + 1 : VSZ - 1;
    const float4* xv = (const float4*)h_new;
    float4 x0 = xv[lane], x1 = xv[lane + 64], x2 = xv[lane + 128], x3 = xv[lane + 192];
    const float4* p0 = (const float4*)(Wg + (size_t)ra * HSZ);
    const float4* p1 = (const float4*)(Wg + (size_t)rb * HSZ);
    float4 a0 = p0[lane], a1 = p0[lane + 64], a2 = p0[lane + 128], a3 = p0[lane + 192];
    float4 b0 = p1[lane], b1 = p1[lane + 64], b2 = p1[lane + 128], b3 = p1[lane + 192];
    float s0 = a0.x * x0.x + a0.y * x0.y + a0.z * x0.z + a0.w * x0.w
             + a1.x * x1.x + a1.y * x1.y + a1.z * x1.z + a1.w * x1.w
             + a2.x * x2.x + a2.y * x2.y + a2.z * x2.z + a2.w * x2.w
             + a3.x * x3.x + a3.y * x3.y + a3.z * x3.z + a3.w * x3.w;
    float s1 = b0.x * x0.x + b0.y * x0.y + b0.z * x0.z + b0.w * x0.w
             + b1.x * x1.x + b1.y * x1.y + b1.z * x1.z + b1.w * x1.w
             + b2.x * x2.x + b2.y * x2.y + b2.z * x2.z + b2.w * x2.w
             + b3.x * x3.x + b3.y * x3.y + b3.z * x3.z + b3.w * x3.w;
#pragma unroll
    for (int o = 32; o > 0; o >>= 1) {
      s0 += __shfl_down(s0, o, 64);
      s1 += __shfl_down(s1, o, 64);
    }
    if (lane == 0) {
      float e = 0.f;
      if (r0 < VSZ) {
        float v = s0 + bg[r0];
        score[r0] = v;
        e += expf(v - SHIFT);
      }
      if (r0 + 1 < VSZ) {
        float v = s1 + bg[r0 + 1];
        score[r0 + 1] = v;
        e += expf(v - SHIFT);
      }
      pr[wave] = e;
    }
    __syncthreads();
    if (tid == 0) atomicAdd(psum, (pr[0] + pr[1]) + (pr[2] + pr[3]));
  }
  // ---- wait-free completion counter; last finisher sums exp(score_c) ----
  __syncthreads();  // drain this block's stores/atomics before the signal
  if (tid == 0) { __threadfence(); lastf = (atomicAdd(cnt, 1) == 512 + 6283 - 1); }
  __syncthreads();
  if (lastf) {
    __threadfence();  // acquire: all GEMM blocks' score_c atomics visible
    __shared__ float red[256];
    float e = 0.f;
    for (int l = tid; l < LSZ; l += 256) e += expf(score[VSZ + l] - SHIFT);
    red[tid] = e; __syncthreads();
    for (int s2 = 128; s2 > 0; s2 >>= 1) { if (tid < s2) red[tid] += red[tid + s2]; __syncthreads(); }
    if (tid == 0) atomicAdd(psum, red[0]);
  }
}

// ============ K6: final probs ============
__global__ void k_final(const float* __restrict__ score, const float* __restrict__ psum,
                        const int* __restrict__ idx, const int* __restrict__ din,
                        const float* __restrict__ enc, float* __restrict__ out) {
  int bid = blockIdx.x, t = threadIdx.x;
  float inv = 1.f / psum[0];
  if (bid < 197) {
    int v = bid * 256 + t;
    if (v < VSZ) atomicAdd(&out[v], expf(score[v] - SHIFT) * inv);
  } else {
    __shared__ float pm[256];
    __shared__ int flag;
    if (t == 0) flag = 0;
    __syncthreads();
    int l0 = (bid - 197) * 256;
    int l = l0 + t;
    float p = expf(score[VSZ + l] - SHIFT) * inv;
    atomicAdd(&out[idx[l]], p);
    int matched = (idx[l] == din[0]);
    pm[t] = matched ? p : 0.f;
    if (matched) atomicExch(&flag, 1);
    __syncthreads();
    if (flag) {
      for (int h = t; h < HSZ; h += 256) {
        float s = 0.f;
        for (int l2 = 0; l2 < 256; ++l2)
          if (pm[l2] != 0.f) s = fmaf(pm[l2], enc[(size_t)(l0 + l2) * HSZ + h], s);
        if (s != 0.f) atomicAdd(&out[VSZ + HSZ + h], s);
      }
    }
  }
}

extern "C" void kernel_launch(void* const* d_in, const int* in_sizes, int n_in,
                              void* d_out, int out_size, void* d_ws, size_t ws_size,
                              hipStream_t stream) {
  const int*   din = (const int*)d_in[0];
  const float* h0  = (const float*)d_in[1];
  const float* enc = (const float*)d_in[2];
  const int*   idx = (const int*)d_in[3];
  const float* emb = (const float*)d_in[4];
  const float* Waw = (const float*)d_in[5];
  const float* baw = (const float*)d_in[6];
  const float* Wau = (const float*)d_in[7];
  const float* bau = (const float*)d_in[8];
  const float* Wih = (const float*)d_in[9];
  const float* bih = (const float*)d_in[10];
  const float* Whh = (const float*)d_in[11];
  const float* bhh = (const float*)d_in[12];
  const float* Wc  = (const float*)d_in[13];
  const float* bc  = (const float*)d_in[14];
  const float* Wg  = (const float*)d_in[15];
  const float* bg  = (const float*)d_in[16];
  float* out = (float*)d_out;
  float* ws  = (float*)d_ws;

  // ws layout (floats), 16B-aligned:
  float* acc    = ws;             // 1024
  float* rnn_in = ws + 1024;      // 1024
  float* gi     = ws + 2048;      // 3072 (+ gh at 5120)
  float* h_new  = ws + 8192;      // 1024
  float* attnw  = ws + 9216;      // 2048
  float* score  = ws + 11264;     // 52305 = [score_g | score_c]
  float* psum   = ws + 63616;     // 1
  int*   cnts   = (int*)(ws + 63620);  // [cnt_gates, cnt_huge]
  unsigned short* bfbuf = (unsigned short*)(ws + 64000);  // enc bf16 (2097152) then Wc bf16 (1048576)
  unsigned short* encB = bfbuf;
  unsigned short* WcB  = bfbuf + 2097152;

  k_attn<<<1479, 256, 0, stream>>>(Waw, baw, din, emb, h0, enc, Wc, attnw, out,
                                   score + VSZ, acc, psum, cnts, bfbuf);
  k_attn_apply<<<128, 256, 0, stream>>>(attnw, enc, acc);
  k_rnn<<<256, 256, 0, stream>>>(Wau, bau, din, emb, acc, rnn_in);
  k_gates<<<1536, 256, 0, stream>>>(Wih, bih, rnn_in, Whh, bhh, h0, gi, h_new, out,
                                    cnts + 0);
  k_huge<<<512 + (VSZ + 7) / 8, 256, 0, stream>>>(encB, WcB, bc, h0, Wg, bg, h_new,
                                                  score, psum, cnts + 1);
  k_final<<<205, 256, 0, stream>>>(score, psum, idx, din, enc, out);
}